// Round 1
// baseline (252.730 us; speedup 1.0000x reference)
//
#include <hip/hip_runtime.h>

// GRU fused kernel for MI355X (gfx950).
// T=24, N=B*X*Y=65536 pixels, F=32 (S16+M8+C8), H=32, 3H=96 gates (r,z,n).
// One wave = 16 pixels for all 24 timesteps. Transposed-gate MFMA formulation:
//   gates^T(96x16) = W(96x32) @ x^T/h^T(32x16), 16x16x32 bf16 MFMA, K=32 in one shot.
// Weights staged in LDS as bf16, biases in LDS fp32 (folded into MFMA C-init).

#define TSTEPS 24
#define NPIX 65536
#define NWAVES 4096   // NPIX / 16

typedef __attribute__((ext_vector_type(8))) short bf16x8;
typedef __attribute__((ext_vector_type(4))) float f32x4;

#define MFMA16(a, b, c) __builtin_amdgcn_mfma_f32_16x16x32_bf16((a), (b), (c), 0, 0, 0)

__device__ __forceinline__ unsigned short f2bf(float f) {
  unsigned u = __builtin_bit_cast(unsigned, f);
  u += 0x7fffu + ((u >> 16) & 1u);   // round-to-nearest-even
  return (unsigned short)(u >> 16);
}

__device__ __forceinline__ float sigmoid_(float x) {
  return __builtin_amdgcn_rcpf(1.f + __expf(-x));
}
__device__ __forceinline__ float tanh_(float x) {
  // 1 - 2/(e^{2x}+1); saturates correctly at +/-inf
  return 1.f - 2.f * __builtin_amdgcn_rcpf(__expf(2.f * x) + 1.f);
}

// h held as two C-layout tiles: hc[ti][reg] = h^T[ti*16 + q*4 + reg][col].
// Produce B-layout fragment: bh[j] = bf16(h^T[q*8+j][col]).
__device__ __forceinline__ bf16x8 relayout_h(const f32x4 h0, const f32x4 h1,
                                             int q, int col) {
  bf16x8 r;
  const int rbase = (q & 1) * 8;
  const bool lowtile = (q < 2);
#pragma unroll
  for (int j = 0; j < 8; ++j) {
    int rr = rbase + j;                       // row within source tile
    int src = ((rr >> 2) << 4) | col;         // source lane
    float v0 = __shfl(h0[j & 3], src, 64);
    float v1 = __shfl(h1[j & 3], src, 64);
    r[j] = f2bf(lowtile ? v0 : v1);
  }
  return r;
}

__global__ __launch_bounds__(256, 4)
void gru_fused(const float* __restrict__ spatial, const float* __restrict__ met,
               const float* __restrict__ ctx,
               const float* __restrict__ W_ih, const float* __restrict__ W_hh,
               const float* __restrict__ b_ih, const float* __restrict__ b_hh,
               const float* __restrict__ Wout, float* __restrict__ out) {
  // bf16 weights: [0]=W_ih, [1]=W_hh, each [96][32] row-major
  __shared__ __align__(16) unsigned short sW[2 * 96 * 32];
  __shared__ __align__(16) float sCB[64];   // b_ih+b_hh rows 0..63 (r,z gates)
  __shared__ __align__(16) float sBIN[32];  // b_ih rows 64..95 (n gate)
  __shared__ __align__(16) float sBHN[32];  // b_hh rows 64..95 (n gate)

  const int tid = threadIdx.x;
  for (int i = tid; i < 96 * 32; i += 256) {
    sW[i] = f2bf(W_ih[i]);
    sW[96 * 32 + i] = f2bf(W_hh[i]);
  }
  if (tid < 64) sCB[tid] = b_ih[tid] + b_hh[tid];
  else if (tid < 96) sBIN[tid - 64] = b_ih[tid];
  else if (tid < 128) sBHN[tid - 96] = b_hh[tid - 32];
  __syncthreads();

  const int wave = blockIdx.x * 4 + (tid >> 6);
  const int lane = tid & 63;
  const int col = lane & 15;     // pixel within group / N-column
  const int q = lane >> 4;       // k-quad
  const long p = (long)wave * 16 + col;   // global pixel

  // per-lane x stream: lane provides x^T[k = q*8 + j][col], j=0..7
  const float* xptr;
  long xstride;
  if (q < 2)       { xptr = spatial + p * 16 + q * 8; xstride = (long)NPIX * 16; }
  else if (q == 2) { xptr = met + p * 8;              xstride = (long)NPIX * 8;  }
  else             { xptr = ctx + p * 8;              xstride = (long)NPIX * 8;  }

  f32x4 h0 = {0.f, 0.f, 0.f, 0.f};
  f32x4 h1 = {0.f, 0.f, 0.f, 0.f};
  const f32x4 zero = {0.f, 0.f, 0.f, 0.f};

  // prefetch t=0
  f32x4 xa = *(const f32x4*)xptr;
  f32x4 xb = *(const f32x4*)(xptr + 4);
  xptr += xstride;

#pragma unroll 1
  for (int t = 0; t < TSTEPS; ++t) {
    // pack current x into B-layout bf16 fragment
    bf16x8 bx;
#pragma unroll
    for (int j = 0; j < 4; ++j) { bx[j] = f2bf(xa[j]); bx[4 + j] = f2bf(xb[j]); }

    // prefetch next step's x
    if (t < TSTEPS - 1) {
      xa = *(const f32x4*)xptr;
      xb = *(const f32x4*)(xptr + 4);
      xptr += xstride;
    }

    // h -> B-layout fragment for the recurrent matmul
    bf16x8 bh = relayout_h(h0, h1, q, col);

    // gx^T = W_ih @ x^T (+ biases in C-init); gh^T = W_hh @ h^T (+ b_hh for n)
    f32x4 G[6], Hv[6];
#pragma unroll
    for (int i = 0; i < 4; ++i) {
      bf16x8 a = *(const bf16x8*)&sW[(i * 16 + col) * 32 + q * 8];
      G[i] = MFMA16(a, bx, *(const f32x4*)&sCB[i * 16 + q * 4]);
    }
    {
      bf16x8 a4 = *(const bf16x8*)&sW[(4 * 16 + col) * 32 + q * 8];
      G[4] = MFMA16(a4, bx, *(const f32x4*)&sBIN[q * 4]);
      bf16x8 a5 = *(const bf16x8*)&sW[(5 * 16 + col) * 32 + q * 8];
      G[5] = MFMA16(a5, bx, *(const f32x4*)&sBIN[16 + q * 4]);
    }
#pragma unroll
    for (int i = 0; i < 4; ++i) {
      bf16x8 a = *(const bf16x8*)&sW[96 * 32 + (i * 16 + col) * 32 + q * 8];
      Hv[i] = MFMA16(a, bh, zero);
    }
    {
      bf16x8 a4 = *(const bf16x8*)&sW[96 * 32 + (4 * 16 + col) * 32 + q * 8];
      Hv[4] = MFMA16(a4, bh, *(const f32x4*)&sBHN[q * 4]);
      bf16x8 a5 = *(const bf16x8*)&sW[96 * 32 + (5 * 16 + col) * 32 + q * 8];
      Hv[5] = MFMA16(a5, bh, *(const f32x4*)&sBHN[16 + q * 4]);
    }

    // gate math, per-lane fp32. Tiles: 0,1=r  2,3=z  4,5=n ; h tiles 0,1.
#pragma unroll
    for (int r = 0; r < 4; ++r) {
      float rv0 = sigmoid_(G[0][r] + Hv[0][r]);
      float rv1 = sigmoid_(G[1][r] + Hv[1][r]);
      float zv0 = sigmoid_(G[2][r] + Hv[2][r]);
      float zv1 = sigmoid_(G[3][r] + Hv[3][r]);
      float nv0 = tanh_(G[4][r] + rv0 * Hv[4][r]);
      float nv1 = tanh_(G[5][r] + rv1 * Hv[5][r]);
      h0[r] = nv0 + zv0 * (h0[r] - nv0);
      h1[r] = nv1 + zv1 * (h1[r] - nv1);
    }
  }

  // out^T(16x16) = W^T(16x32) @ h^T(32x16)
  bf16x8 bhf = relayout_h(h0, h1, q, col);
  bf16x8 aw;
#pragma unroll
  for (int j = 0; j < 8; ++j) aw[j] = f2bf(Wout[(q * 8 + j) * 16 + col]);
  f32x4 o = MFMA16(aw, bhf, zero);
  // D[m=s=q*4+reg][n=pixel=col] -> out[p*16 + s], 4 consecutive s per lane
  *(f32x4*)&out[p * 16 + q * 4] = o;
}

extern "C" void kernel_launch(void* const* d_in, const int* in_sizes, int n_in,
                              void* d_out, int out_size, void* d_ws, size_t ws_size,
                              hipStream_t stream) {
  const float* spatial = (const float*)d_in[0];
  const float* met     = (const float*)d_in[1];
  const float* ctx     = (const float*)d_in[2];
  const float* W_ih    = (const float*)d_in[3];
  const float* W_hh    = (const float*)d_in[4];
  const float* b_ih    = (const float*)d_in[5];
  const float* b_hh    = (const float*)d_in[6];
  const float* Wout    = (const float*)d_in[7];
  float* out = (float*)d_out;

  gru_fused<<<dim3(NWAVES / 4), dim3(256), 0, stream>>>(
      spatial, met, ctx, W_ih, W_hh, b_ih, b_hh, Wout, out);
}